// Round 5
// baseline (956.849 us; speedup 1.0000x reference)
//
#include <hip/hip_runtime.h>
#include <hip/hip_bf16.h>
#include <stdint.h>

#define F 256            // IN_F == OUT_F == 256

typedef short bhalf8 __attribute__((ext_vector_type(8)));
typedef unsigned short ushort8v __attribute__((ext_vector_type(8)));
typedef float f32x4 __attribute__((ext_vector_type(4)));
typedef int i32x4 __attribute__((ext_vector_type(4)));

__device__ __forceinline__ unsigned short f2b(float f) {
    union { float f; uint32_t u; } x; x.f = f;
    uint32_t u = x.u;
    return (unsigned short)((u + 0x7FFFu + ((u >> 16) & 1u)) >> 16);
}
__device__ __forceinline__ float b2f(unsigned short h) {
    union { uint32_t u; float f; } x; x.u = ((uint32_t)h) << 16;
    return x.f;
}

// ---------------------------------------------------------------------------
// W prep: f32 W[k][n] -> bf16, pre-tiled per K-step: Wt[sel][ks][n][kk]
// (sel: 0=mean 1=var; ks = k/32; kk = k%32). 128 KB total, L2-resident.
// ---------------------------------------------------------------------------
__global__ __launch_bounds__(256) void wprep_kernel(
    const float* __restrict__ Wm, const float* __restrict__ Wv,
    unsigned short* __restrict__ Wt)
{
    int idx = blockIdx.x * 256 + threadIdx.x;   // 4096 = 2 sel * 8 ks * 256 n
    int sel = idx >> 11;
    int ks  = (idx >> 8) & 7;
    int n   = idx & 255;
    const float* W = sel ? Wv : Wm;
    unsigned short* dst = Wt + ((size_t)sel * 8 * 256 * 32) + ((size_t)(ks * 256 + n) * 32);
    #pragma unroll
    for (int kk = 0; kk < 32; ++kk)
        dst[kk] = f2b(W[(ks * 32 + kk) * 256 + n]);
}

// ---------------------------------------------------------------------------
// Dense v2: m' = elu(mean@Wm + bm) * att ;  v' = relu(var@Wv + bv) * att^2
// att = exp(-relu(var@Wv+bv)). Output bf16 interleaved mv[row][512].
// 64 rows/block, 8 waves. A (both mats, full K) staged ONCE into 64KB
// XOR-swizzled LDS; B-frags read directly from L2/L1-resident Wt.
// ONE barrier per block; the K-loop has no syncs at all.
// ---------------------------------------------------------------------------
__global__ __launch_bounds__(512, 4) void dense_kernel(
    const float* __restrict__ mean, const float* __restrict__ var,
    const unsigned short* __restrict__ Wt,
    const float* __restrict__ bm, const float* __restrict__ bv,
    unsigned short* __restrict__ mv, int N)
{
    // As[mat][row][k] with k XOR-swizzled: k' = k ^ ((row&7)<<3)  (shorts)
    __shared__ unsigned short As[2][64 * 256];   // 64 KB exactly

    const int tid  = threadIdx.x;
    const int row0 = blockIdx.x * 64;

    // ---- one-shot A staging: thread t covers row t>>3, k block (t&7)*32
    {
        const int srow = tid >> 3;
        const int kq   = (tid & 7) * 32;
        int sgrow = row0 + srow; if (sgrow >= N) sgrow = N - 1;
        const float* pm = &mean[(size_t)sgrow * F + kq];
        const float* pv = &var [(size_t)sgrow * F + kq];
        unsigned short* dm = &As[0][srow * 256];
        unsigned short* dv = &As[1][srow * 256];
        const int sw = (srow & 7) << 3;
        #pragma unroll
        for (int j = 0; j < 8; ++j) {
            f32x4 a = *(const f32x4*)(pm + j * 4);
            f32x4 b = *(const f32x4*)(pv + j * 4);
            int kx = (kq + j * 4) ^ sw;          // stays 4-aligned
            ushort4 ua = { f2b(a[0]), f2b(a[1]), f2b(a[2]), f2b(a[3]) };
            ushort4 ub = { f2b(b[0]), f2b(b[1]), f2b(b[2]), f2b(b[3]) };
            *(ushort4*)(dm + kx) = ua;
            *(ushort4*)(dv + kx) = ub;
        }
    }
    __syncthreads();

    const int lane = tid & 63;
    const int w    = tid >> 6;
    const int wr   = w >> 2;          // 0..1 : 32-row half
    const int wc   = w & 3;           // 0..3 : 64-col slice
    const int lr   = lane & 15;
    const int lk   = lane >> 4;

    f32x4 accm[2][4], accv[2][4];
    #pragma unroll
    for (int i = 0; i < 2; ++i)
        #pragma unroll
        for (int j = 0; j < 4; ++j) { accm[i][j] = (f32x4)0.f; accv[i][j] = (f32x4)0.f; }

    const int rA0 = wr * 32 + lr;
    const int rA1 = rA0 + 16;
    const unsigned short* a0m = &As[0][rA0 * 256];
    const unsigned short* a1m = &As[0][rA1 * 256];
    const unsigned short* a0v = &As[1][rA0 * 256];
    const unsigned short* a1v = &As[1][rA1 * 256];
    const int sw0 = (rA0 & 7) << 3;
    const int sw1 = (rA1 & 7) << 3;

    #pragma unroll
    for (int ks = 0; ks < 8; ++ks) {
        const int k = ks * 32 + lk * 8;
        bhalf8 am0 = *(const bhalf8*)(a0m + (k ^ sw0));
        bhalf8 am1 = *(const bhalf8*)(a1m + (k ^ sw1));
        bhalf8 av0 = *(const bhalf8*)(a0v + (k ^ sw0));
        bhalf8 av1 = *(const bhalf8*)(a1v + (k ^ sw1));

        const unsigned short* Bm = Wt + ((size_t)(ks * 256 + wc * 64 + lr) * 32) + lk * 8;
        const unsigned short* Bv = Bm + (size_t)8 * 256 * 32;
        #pragma unroll
        for (int ct = 0; ct < 4; ++ct) {
            bhalf8 bmf = *(const bhalf8*)(Bm + ct * 512);
            bhalf8 bvf = *(const bhalf8*)(Bv + ct * 512);
            accm[0][ct] = __builtin_amdgcn_mfma_f32_16x16x32_bf16(am0, bmf, accm[0][ct], 0, 0, 0);
            accm[1][ct] = __builtin_amdgcn_mfma_f32_16x16x32_bf16(am1, bmf, accm[1][ct], 0, 0, 0);
            accv[0][ct] = __builtin_amdgcn_mfma_f32_16x16x32_bf16(av0, bvf, accv[0][ct], 0, 0, 0);
            accv[1][ct] = __builtin_amdgcn_mfma_f32_16x16x32_bf16(av1, bvf, accv[1][ct], 0, 0, 0);
        }
    }

    // epilogue: bias + elu/relu + attention, store bf16 interleaved
    #pragma unroll
    for (int rt = 0; rt < 2; ++rt) {
        #pragma unroll
        for (int ct = 0; ct < 4; ++ct) {
            const int col = wc * 64 + ct * 16 + lr;
            const float bmc = bm[col], bvc = bv[col];
            #pragma unroll
            for (int q = 0; q < 4; ++q) {
                int grow = row0 + wr * 32 + rt * 16 + lk * 4 + q;
                if (grow < N) {
                    float mp = accm[rt][ct][q] + bmc;
                    float vp = accv[rt][ct][q] + bvc;
                    float me = mp > 0.f ? mp : (__expf(mp) - 1.f);
                    float vr = vp > 0.f ? vp : 0.f;
                    float att = __expf(-vr);
                    mv[(size_t)grow * 512 + col]       = f2b(me * att);
                    mv[(size_t)grow * 512 + 256 + col] = f2b(vr * att * att);
                }
            }
        }
    }
}

// ---------------------------------------------------------------------------
// CSR build
// ---------------------------------------------------------------------------
__global__ void hist_kernel(const int* __restrict__ row, int E, int* __restrict__ count) {
    int i = blockIdx.x * blockDim.x + threadIdx.x;
    if (i < E) {
        int r = __builtin_nontemporal_load(&row[i]);
        atomicAdd(&count[r], 1);
    }
}

__global__ __launch_bounds__(256) void scan1_kernel(const int* __restrict__ count, int N,
                                                    int* __restrict__ offs, int* __restrict__ bsums)
{
    __shared__ int sd[256];
    int t  = threadIdx.x;
    int gi = blockIdx.x * 1024 + t * 4;
    int c[4];
    #pragma unroll
    for (int q = 0; q < 4; ++q) c[q] = (gi + q < N) ? count[gi + q] : 0;
    int s = c[0] + c[1] + c[2] + c[3];
    sd[t] = s; __syncthreads();
    int acc = s;
    for (int off = 1; off < 256; off <<= 1) {
        int u = (t >= off) ? sd[t - off] : 0;
        __syncthreads();
        acc += u; sd[t] = acc;
        __syncthreads();
    }
    int run = acc - s;
    #pragma unroll
    for (int q = 0; q < 4; ++q) { if (gi + q < N) offs[gi + q] = run; run += c[q]; }
    if (t == 255) bsums[blockIdx.x] = acc;
}

__global__ __launch_bounds__(128) void scan2_kernel(int* __restrict__ bsums, int SB,
                                                    int* __restrict__ offs, int N)
{
    __shared__ int sd[128];
    int t = threadIdx.x;
    int v = (t < SB) ? bsums[t] : 0;
    sd[t] = v; __syncthreads();
    int acc = v;
    for (int off = 1; off < 128; off <<= 1) {
        int u = (t >= off) ? sd[t - off] : 0;
        __syncthreads();
        acc += u; sd[t] = acc;
        __syncthreads();
    }
    if (t < SB) bsums[t] = acc - v;
    if (t == 127) offs[N] = sd[127];
}

__global__ __launch_bounds__(256) void scan3_kernel(int* __restrict__ offs, int N,
                                                    const int* __restrict__ bsums)
{
    int b  = bsums[blockIdx.x];
    int gi = blockIdx.x * 1024 + threadIdx.x * 4;
    #pragma unroll
    for (int q = 0; q < 4; ++q) if (gi + q < N) offs[gi + q] += b;
}

__global__ void fill_kernel(const int* __restrict__ row, const int* __restrict__ col,
                            const float* __restrict__ a0, const float* __restrict__ a1,
                            int E, int* __restrict__ cursor, i32x4* __restrict__ rec)
{
    int i = blockIdx.x * blockDim.x + threadIdx.x;
    if (i < E) {
        int   r  = __builtin_nontemporal_load(&row[i]);
        int   c  = __builtin_nontemporal_load(&col[i]);
        float v0 = __builtin_nontemporal_load(&a0[i]);
        float v1 = __builtin_nontemporal_load(&a1[i]);
        int pos = atomicAdd(&cursor[r], 1);
        i32x4 rc;
        rc[0] = c;
        rc[1] = __float_as_int(v0);
        rc[2] = __float_as_int(v1);
        rc[3] = 0;
        rec[pos] = rc;
    }
}

// ---------------------------------------------------------------------------
// Fused SpMM (unchanged from R4): 1 wave per node; 8-deep gather batches,
// next batch's records prefetched while gathers are in flight.
// ---------------------------------------------------------------------------
__global__ __launch_bounds__(256) void spmm_kernel(
    const int* __restrict__ offs, const int* __restrict__ rec,
    const unsigned short* __restrict__ mv,
    float* __restrict__ out, int N)
{
    int w    = threadIdx.x >> 6;
    int lane = threadIdx.x & 63;
    int node = blockIdx.x * 4 + w;
    if (node >= N) return;
    int s = offs[node], e = offs[node + 1];

    const bool isv = lane >= 32;
    const int  fb  = (lane & 31) * 8;
    const unsigned short* base = mv + (isv ? 256 : 0) + fb;
    const int woff = isv ? 2 : 1;

    float acc[8];
    #pragma unroll
    for (int q = 0; q < 8; ++q) acc[q] = 0.f;

    const int cnt = e - s;
    const int nb  = cnt >> 3;
    const int* rp = rec + (size_t)s * 4;

    if (nb > 0) {
        int   c[8];
        float wt[8];
        #pragma unroll
        for (int q = 0; q < 8; ++q) {
            c[q]  = __builtin_nontemporal_load(rp + q * 4);
            wt[q] = __int_as_float(__builtin_nontemporal_load(rp + q * 4 + woff));
        }
        for (int b = 0; b < nb; ++b) {
            ushort8v p[8];
            #pragma unroll
            for (int q = 0; q < 8; ++q)
                p[q] = *(const ushort8v*)(base + (size_t)c[q] * 512);
            int   cn[8];
            float wn[8];
            if (b + 1 < nb) {
                const int* rn = rp + 32;
                #pragma unroll
                for (int q = 0; q < 8; ++q) {
                    cn[q] = __builtin_nontemporal_load(rn + q * 4);
                    wn[q] = __int_as_float(__builtin_nontemporal_load(rn + q * 4 + woff));
                }
            }
            #pragma unroll
            for (int q = 0; q < 8; ++q) {
                #pragma unroll
                for (int t = 0; t < 8; ++t) acc[t] += wt[q] * b2f(p[q][t]);
            }
            #pragma unroll
            for (int q = 0; q < 8; ++q) { c[q] = cn[q]; wt[q] = wn[q]; }
            rp += 32;
        }
    }
    for (int j = s + nb * 8; j < e; ++j) {
        const int* rj = rec + (size_t)j * 4;
        int   cc = rj[0];
        float a  = __int_as_float(rj[woff]);
        ushort8v p = *(const ushort8v*)(base + (size_t)cc * 512);
        #pragma unroll
        for (int t = 0; t < 8; ++t) acc[t] += a * b2f(p[t]);
    }

    float* obase = out + (isv ? (size_t)N * F : 0) + (size_t)node * F + fb;
    float4 o0 = { acc[0], acc[1], acc[2], acc[3] };
    float4 o1 = { acc[4], acc[5], acc[6], acc[7] };
    *(float4*)obase       = o0;
    *(float4*)(obase + 4) = o1;
}

// ---------------------------------------------------------------------------
extern "C" void kernel_launch(void* const* d_in, const int* in_sizes, int n_in,
                              void* d_out, int out_size, void* d_ws, size_t ws_size,
                              hipStream_t stream)
{
    const float* mean = (const float*)d_in[0];
    const float* var  = (const float*)d_in[1];
    const float* Wm   = (const float*)d_in[2];
    const float* bm   = (const float*)d_in[3];
    const float* Wv   = (const float*)d_in[4];
    const float* bv   = (const float*)d_in[5];
    const int*   erow = (const int*)d_in[6];
    const int*   ecol = (const int*)d_in[7];
    const float* a0   = (const float*)d_in[8];
    const float* a1   = (const float*)d_in[9];

    const int N = in_sizes[0] / F;     // 100000
    const int E = in_sizes[6];         // 3200000

    uintptr_t p = (uintptr_t)d_ws;
    auto take = [&](size_t bytes) {
        uintptr_t r = (p + 255) & ~(uintptr_t)255;
        p = r + bytes;
        return (void*)r;
    };
    unsigned short* mv     = (unsigned short*)take((size_t)N * 512 * 2);
    int*            rec    = (int*)take((size_t)E * 16);
    int*            count  = (int*)take((size_t)N * 4);
    int*            offs   = (int*)take((size_t)(N + 1) * 4);
    int*            cursor = (int*)take((size_t)N * 4);
    int*            bsums  = (int*)take(1024 * 4);
    unsigned short* Wt     = (unsigned short*)take((size_t)2 * 8 * 256 * 32 * 2);

    const int SB = (N + 1023) / 1024;

    hipMemsetAsync(count, 0, (size_t)N * 4, stream);

    wprep_kernel<<<16, 256, 0, stream>>>(Wm, Wv, Wt);
    dense_kernel<<<(N + 63) / 64, 512, 0, stream>>>(mean, var, Wt, bm, bv, mv, N);

    hist_kernel<<<(E + 255) / 256, 256, 0, stream>>>(erow, E, count);
    scan1_kernel<<<SB, 256, 0, stream>>>(count, N, offs, bsums);
    scan2_kernel<<<1, 128, 0, stream>>>(bsums, SB, offs, N);
    scan3_kernel<<<SB, 256, 0, stream>>>(offs, N, bsums);
    hipMemcpyAsync(cursor, offs, (size_t)N * 4, hipMemcpyDeviceToDevice, stream);
    fill_kernel<<<(E + 255) / 256, 256, 0, stream>>>(erow, ecol, a0, a1, E, cursor, (i32x4*)rec);

    spmm_kernel<<<(N + 3) / 4, 256, 0, stream>>>(offs, rec, mv, (float*)d_out, N);
}